// Round 14
// baseline (1116.966 us; speedup 1.0000x reference)
//
#include <hip/hip_runtime.h>
#include <math.h>

#define DIMX 512
#define HEADS 8
#define DHEAD 64
#define NBFX 256
#define FFD 2048
#define NBX 4
#define SEQ 8192
#define TOK (NBX*SEQ)     // 32768 tokens
#define NBH (NBX*HEADS)   // 32 (b,h) pairs
#define VROWS 80          // 64 v-dims + ones row(64) + zeros pad
#define NCHUNK 8          // ctx K-split chunks (1024 tokens each)
#define BK 64

typedef unsigned short u16;
typedef __attribute__((ext_vector_type(8))) short short8;
typedef __attribute__((ext_vector_type(4))) float f32x4;

__device__ __forceinline__ float bf2f(u16 x){ return __uint_as_float(((unsigned)x)<<16); }
__device__ __forceinline__ u16 f2bf(float f){
  unsigned u=__float_as_uint(f);
  return (u16)((u + 0x7FFFu + ((u>>16)&1u))>>16);
}
__device__ __forceinline__ void gload16(const void* g, void* l){
  __builtin_amdgcn_global_load_lds((const __attribute__((address_space(1))) void*)g,
                                   (__attribute__((address_space(3))) void*)l, 16, 0, 0);
}
// exact-GELU via A&S 7.1.26 erf approx (max erf err 1.5e-7)
__device__ __forceinline__ float gelu_f(float v){
  float x=v*0.70710678118654752f;
  float ax=fabsf(x);
  float t=1.0f/(1.0f+0.3275911f*ax);
  float p=t*(0.254829592f+t*(-0.284496736f+t*(1.421413741f+t*(-1.453152027f+t*1.061405429f))));
  float erfv=1.0f-p*__expf(-ax*ax);
  erfv=(x<0.0f)? -erfv : erfv;
  return 0.5f*v*(1.0f+erfv);
}

// ---------------- prep / elementwise ----------------
__global__ void copy_f32(const float4* __restrict__ s, float4* __restrict__ d, int n4){
  int i=blockIdx.x*blockDim.x+threadIdx.x;
  if(i<n4) d[i]=s[i];
}
__global__ void conv_proj(const float* __restrict__ p, u16* __restrict__ o, int n){
  int i=blockIdx.x*blockDim.x+threadIdx.x;
  if(i<n) o[i]=f2bf(p[i]*0.35355339059327373f); // fold d^-0.25 into proj
}
// src fp32 [K][Ncol] -> dst bf16 [Ncol][K] (transposed)
__global__ void convT(const float* __restrict__ src, u16* __restrict__ dst, int K, int Ncol){
  __shared__ float t[32][33];
  int k0=blockIdx.y*32, n0=blockIdx.x*32;
  int tx=threadIdx.x, ty=threadIdx.y;
  for(int i=ty;i<32;i+=8) t[i][tx]=src[(size_t)(k0+i)*Ncol + n0+tx];
  __syncthreads();
  for(int i=ty;i<32;i+=8) dst[(size_t)(n0+i)*K + k0+tx]=f2bf(t[tx][i]);
}
__global__ void fill_vt(u16* __restrict__ vt){
  int i=blockIdx.x*blockDim.x+threadIdx.x; // < NBH*16*SEQ = 2^22
  int n=i&(SEQ-1); int r=(i>>13)&15; int bh=i>>17;
  vt[((size_t)bh*VROWS + 64 + r)*SEQ + n] = (r==0)? (u16)0x3F80 : (u16)0;
}
__global__ void pack_bias(const float* __restrict__ bq, const float* __restrict__ bk,
                          const float* __restrict__ bv, float* __restrict__ o){
  int i=blockIdx.x*blockDim.x+threadIdx.x; // 2*1536
  int l=i/1536, c=i-l*1536;
  const float* s=(c<512)? bq : ((c<1024)? bk : bv);
  o[i]=s[l*512 + (c&511)];
}

// wave-per-row LN over bf16 trunk
__global__ __launch_bounds__(256) void ln_k(const u16* __restrict__ x, const float* __restrict__ g,
                                            const float* __restrict__ b, u16* __restrict__ y){
  const int row=blockIdx.x*4 + (threadIdx.x>>6);
  const int ln=threadIdx.x&63;
  const u16* xr=x+(size_t)row*DIMX;
  short8 xv=*(const short8*)(xr+ln*8);
  float v[8];
  #pragma unroll
  for(int e=0;e<8;e++) v[e]=bf2f((u16)xv[e]);
  float s=0;
  #pragma unroll
  for(int e=0;e<8;e++) s+=v[e];
  #pragma unroll
  for(int m=1;m<64;m<<=1) s+=__shfl_xor(s,m);
  const float mean=s*(1.0f/DIMX);
  float s2=0;
  #pragma unroll
  for(int e=0;e<8;e++){ v[e]-=mean; s2+=v[e]*v[e]; }
  #pragma unroll
  for(int m=1;m<64;m<<=1) s2+=__shfl_xor(s2,m);
  const float rs=rsqrtf(s2*(1.0f/DIMX)+1e-5f);
  u16* yr=y+(size_t)row*DIMX+ln*8;
  u16 pk[8];
  #pragma unroll
  for(int e=0;e<8;e++) pk[e]=f2bf(v[e]*rs*g[ln*8+e]+b[ln*8+e]);
  uint4 pv;
  pv.x=(unsigned)pk[0]|((unsigned)pk[1]<<16); pv.y=(unsigned)pk[2]|((unsigned)pk[3]<<16);
  pv.z=(unsigned)pk[4]|((unsigned)pk[5]<<16); pv.w=(unsigned)pk[6]|((unsigned)pk[7]<<16);
  *(uint4*)yr=pv;
}
// wave-per-row LN over fp32 input (layer-0 entry)
__global__ __launch_bounds__(256) void ln_f32(const float* __restrict__ x, const float* __restrict__ g,
                                              const float* __restrict__ b, u16* __restrict__ y){
  const int row=blockIdx.x*4 + (threadIdx.x>>6);
  const int ln=threadIdx.x&63;
  const float* xr=x+(size_t)row*DIMX;
  float4 v0=*(const float4*)&xr[ln*8];
  float4 v1=*(const float4*)&xr[ln*8+4];
  float v[8]={v0.x,v0.y,v0.z,v0.w,v1.x,v1.y,v1.z,v1.w};
  float s=0;
  #pragma unroll
  for(int e=0;e<8;e++) s+=v[e];
  #pragma unroll
  for(int m=1;m<64;m<<=1) s+=__shfl_xor(s,m);
  const float mean=s*(1.0f/DIMX);
  float s2=0;
  #pragma unroll
  for(int e=0;e<8;e++){ v[e]-=mean; s2+=v[e]*v[e]; }
  #pragma unroll
  for(int m=1;m<64;m<<=1) s2+=__shfl_xor(s2,m);
  const float rs=rsqrtf(s2*(1.0f/DIMX)+1e-5f);
  u16* yr=y+(size_t)row*DIMX+ln*8;
  u16 pk[8];
  #pragma unroll
  for(int e=0;e<8;e++) pk[e]=f2bf(v[e]*rs*g[ln*8+e]+b[ln*8+e]);
  uint4 pv;
  pv.x=(unsigned)pk[0]|((unsigned)pk[1]<<16); pv.y=(unsigned)pk[2]|((unsigned)pk[3]<<16);
  pv.z=(unsigned)pk[4]|((unsigned)pk[5]<<16); pv.w=(unsigned)pk[6]|((unsigned)pk[7]<<16);
  *(uint4*)yr=pv;
}

// ---------------- 256x256 single-buffered 2-barrier GEMM (m97 structure, 2 blocks/CU) ----------------
// EPI 0: QKV (q/k bf16 + vT); 1: bf16 trunk +=; 2: gelu->bf16;
// 3: bf16_out = f2bf(aux_f32 + acc + b); 4: f32_out = bf2f(aux_bf16) + acc + b
#define MFMA16(MH,BF,NH) do{                                                             \
  __builtin_amdgcn_s_setprio(1);                                                         \
  _Pragma("unroll") for(int kk_=0;kk_<2;kk_++)                                           \
    _Pragma("unroll") for(int i_=0;i_<4;i_++)                                            \
      _Pragma("unroll") for(int j_=0;j_<2;j_++)                                          \
        acc[MH][i_][NH][j_]=__builtin_amdgcn_mfma_f32_16x16x32_bf16(af[i_][kk_],BF[j_][kk_],acc[MH][i_][NH][j_],0,0,0); \
  __builtin_amdgcn_s_setprio(0);                                                         \
}while(0)

// stage half-tile (2 gloads/thread) of tile T
#define STG(T,HALF,ISB) do{                                                              \
  gload16(gp[ISB][HALF][0]+(size_t)(T)*BK, &lds[ISB][(HALF)*128 +    wv*8][0]);          \
  gload16(gp[ISB][HALF][1]+(size_t)(T)*BK, &lds[ISB][(HALF)*128 + 64+wv*8][0]); }while(0)

#define LDA(MH) do{                                                                      \
  _Pragma("unroll") for(int i_=0;i_<4;i_++)                                              \
    _Pragma("unroll") for(int kk_=0;kk_<2;kk_++)                                         \
      af[i_][kk_]=*(const short8*)((const u16*)lds[0] + aoffs[MH][i_][kk_]); }while(0)

#define LDB(BF,NH) do{                                                                   \
  _Pragma("unroll") for(int j_=0;j_<2;j_++)                                              \
    _Pragma("unroll") for(int kk_=0;kk_<2;kk_++)                                         \
      BF[j_][kk_]=*(const short8*)((const u16*)lds[1] + boffs[NH][j_][kk_]); }while(0)

template<int EPI,int K>
__global__ __launch_bounds__(512,2) void gemm256(const u16* __restrict__ A, const u16* __restrict__ Bt,
                                                 const float* __restrict__ bias, void* __restrict__ outp,
                                                 u16* __restrict__ out2, const void* __restrict__ aux,
                                                 int Ncol){
  constexpr int nt=K/BK;
  constexpr int HS=(K==2048)?1:2;       // band height log2
  constexpr int H=1<<HS;
  __shared__ u16 lds[2][256][64];       // single buffer, 64 KB -> 2 blocks/CU (reg-permitting)
  const int tid=threadIdx.x, wv=tid>>6, ln=tid&63;
  const int wr=wv>>2, wc=wv&3;
  const int gx=gridDim.x;
  const int P=blockIdx.y*gx+blockIdx.x;
  const int grp=8*H*gx;
  const int G=P/grp, R=P-G*grp;
  const int xcd=R&7, s=R>>3;
  const int by=(G*8+xcd)*H + (s&(H-1));
  const int bx=s>>HS;
  const int m0=by*256, n0=bx*256;
  f32x4 acc[2][4][2][2]={};

  const u16* gp[2][2][2];
  #pragma unroll
  for(int isB=0;isB<2;isB++)
    #pragma unroll
    for(int half=0;half<2;half++)
      #pragma unroll
      for(int ss=0;ss<2;ss++){
        int Gg=ss*512+wv*64+ln;
        int arow=half*128+(Gg>>3), g=Gg&7;
        const u16* src=isB? Bt:A;
        int b0=isB? n0:m0;
        gp[isB][half][ss]=src+(size_t)(b0+arow)*K+((g^(arow&7))<<3);
      }
  int aoffs[2][4][2], boffs[2][2][2];
  #pragma unroll
  for(int mh=0;mh<2;mh++)
    #pragma unroll
    for(int i=0;i<4;i++){
      int row=wr*128+mh*64+i*16+(ln&15);
      #pragma unroll
      for(int kk=0;kk<2;kk++)
        aoffs[mh][i][kk]=row*64+((((kk*4+(ln>>4)))^(row&7))<<3);
    }
  #pragma unroll
  for(int nh=0;nh<2;nh++)
    #pragma unroll
    for(int j=0;j<2;j++){
      int row=wc*64+nh*32+j*16+(ln&15);
      #pragma unroll
      for(int kk=0;kk<2;kk++)
        boffs[nh][j][kk]=row*64+((((kk*4+(ln>>4)))^(row&7))<<3);
    }

  short8 af[4][2], bf0[2][2], bf1[2][2];

  #pragma unroll 1
  for(int t=0;t<nt;t++){
    STG(t,0,0); STG(t,1,0); STG(t,0,1); STG(t,1,1);  // 8 loads/thread, full tile
    __syncthreads();                                  // drains vmcnt + barrier
    LDB(bf0,0); LDA(0);
    MFMA16(0,bf0,0);
    LDB(bf1,1);
    MFMA16(0,bf1,1);
    LDA(1);
    MFMA16(1,bf0,0);
    MFMA16(1,bf1,1);
    __syncthreads();                                  // reads done before re-stage
  }

  // epilogue
  #pragma unroll
  for(int mh=0;mh<2;mh++)
  #pragma unroll
  for(int i=0;i<4;i++)
  #pragma unroll
  for(int nh=0;nh<2;nh++)
  #pragma unroll
  for(int j=0;j<2;j++){
    const int row=m0+wr*128+mh*64+i*16+(ln>>4)*4;
    const int col=n0+wc*64+nh*32+j*16+(ln&15);
    const float bv=bias[col];
    const f32x4 a=acc[mh][i][nh][j];
    if constexpr(EPI==0){
      if(col<1024){
        u16* o=(u16*)outp + (size_t)(col>>9)*TOK*DIMX + (col&511);
        #pragma unroll
        for(int r=0;r<4;r++) o[(size_t)(row+r)*DIMX]=f2bf(a[r]+bv);
      } else {
        const int hd=col-1024, h_=hd>>6, d_=hd&63, b_=row>>13, nn=row&(SEQ-1);
        u16 pk[4];
        #pragma unroll
        for(int r=0;r<4;r++) pk[r]=f2bf(a[r]+bv);
        uint2 pv; pv.x=(unsigned)pk[0]|((unsigned)pk[1]<<16); pv.y=(unsigned)pk[2]|((unsigned)pk[3]<<16);
        *(uint2*)&out2[((size_t)(b_*HEADS+h_)*VROWS+d_)*SEQ+nn]=pv;
      }
    } else if constexpr(EPI==1){ // bf16 trunk residual RMW
      u16* o=(u16*)outp;
      #pragma unroll
      for(int r=0;r<4;r++){
        size_t ix=(size_t)(row+r)*Ncol+col;
        o[ix]=f2bf(bf2f(o[ix])+a[r]+bv);
      }
    } else if constexpr(EPI==2){
      u16* o=(u16*)outp;
      #pragma unroll
      for(int r=0;r<4;r++)
        o[(size_t)(row+r)*Ncol+col]=f2bf(gelu_f(a[r]+bv));
    } else if constexpr(EPI==3){ // bf16 trunk = fp32 aux + acc + b
      u16* o=(u16*)outp;
      const float* ax=(const float*)aux;
      #pragma unroll
      for(int r=0;r<4;r++){
        size_t ix=(size_t)(row+r)*Ncol+col;
        o[ix]=f2bf(ax[ix]+a[r]+bv);
      }
    } else { // EPI==4: fp32 out = bf16 aux + acc + b
      float* o=(float*)outp;
      const u16* ax=(const u16*)aux;
      #pragma unroll
      for(int r=0;r<4;r++){
        size_t ix=(size_t)(row+r)*Ncol+col;
        o[ix]=bf2f(ax[ix])+a[r]+bv;
      }
    }
  }
}

// ---------------- vsum: per (bh,d<=64) row-sum of vT over all n ----------------
__global__ __launch_bounds__(256) void vsum_k(const u16* __restrict__ vt, float* __restrict__ vs){
  const int gw=blockIdx.x*4 + (threadIdx.x>>6); // 0..2079 = 32*65
  const int ln=threadIdx.x&63;
  const int bh=gw/65, d=gw-bh*65;
  const u16* row=vt+((size_t)bh*VROWS+d)*SEQ;
  float s=0;
  for(int it=0;it<16;it++){
    short8 v=*(const short8*)&row[it*512+ln*8];
    #pragma unroll
    for(int e=0;e<8;e++) s+=bf2f((u16)v[e]);
  }
  #pragma unroll
  for(int m=1;m<64;m<<=1) s+=__shfl_xor(s,m);
  if(ln==0) vs[bh*80+d]=s;
}

// ---------------- fused k-features + ctx partial GEMM (deferred max, 8 waves) ----------------
__global__ __launch_bounds__(512) void kctx(const u16* __restrict__ kb, const u16* __restrict__ pj,
                                            const u16* __restrict__ vt,
                                            float* __restrict__ part, float* __restrict__ maxb){
  __shared__ u16 kl[64*64];     // [token][d], granule-swizzled by token&7
  __shared__ u16 vl[80*64];     // [d][n],     granule-swizzled by d&7
  __shared__ u16 kp_l[256*64];  // [m][n], granule-swizzled (per-wave rows)
  __shared__ float dgl[64];
  const int kc=blockIdx.x, bh=blockIdx.y, b_=bh>>3, h_=bh&7;
  const int tid=threadIdx.x, wv=tid>>6, ln=tid&63;
  short8 pjf[2][2];
  #pragma unroll
  for(int i=0;i<2;i++)
    #pragma unroll
    for(int t=0;t<2;t++)
      pjf[i][t]=*(const short8*)&pj[(size_t)(wv*32+i*16+(ln&15))*DHEAD + t*32 + (ln>>4)*8];
  f32x4 ctx[2][5]={};
  float m_run=-3.0e38f;
  const u16* vbh=vt+(size_t)bh*VROWS*SEQ;
  for(int s=0;s<16;s++){
    const int n0s=kc*1024+s*64;
    const u16* kg=kb+((size_t)(b_*SEQ+n0s))*DIMX + h_*DHEAD;
    { // kl: 512 granules, 1/thread
      int t=tid>>3, g=tid&7;
      gload16(kg+(size_t)t*DIMX+((g^(t&7))*8), &kl[(size_t)tid*8]);
    }
    { // vl rows 0..63: 1/thread
      int d=tid>>3, g=tid&7;
      gload16(vbh+(size_t)d*SEQ+n0s+((g^(d&7))*8), &vl[(size_t)tid*8]);
    }
    if(tid<128){ // vl rows 64..79
      int c=512+tid; int d=c>>3, g=c&7;
      gload16(vbh+(size_t)d*SEQ+n0s+((g^(d&7))*8), &vl[(size_t)c*8]);
    }
    __syncthreads();
    if(tid<64){
      float ss=0;
      #pragma unroll
      for(int gg=0;gg<8;gg++){
        short8 kv=*(const short8*)&kl[tid*64 + ((gg+tid)&7)*8];
        #pragma unroll
        for(int e=0;e<8;e++){ float x=bf2f((u16)kv[e]); ss+=x*x; }
      }
      dgl[tid]=ss*0.0625f; // 0.5 * d^-0.5
    }
    __syncthreads();
    f32x4 dd[2][4]={};
    #pragma unroll
    for(int tk=0;tk<2;tk++)
      #pragma unroll
      for(int j=0;j<4;j++){
        short8 bk_=*(const short8*)&kl[(j*16+(ln&15))*64 + (((tk*4+(ln>>4))^(ln&7))<<3)];
        #pragma unroll
        for(int i=0;i<2;i++)
          dd[i][j]=__builtin_amdgcn_mfma_f32_16x16x32_bf16(pjf[i][tk],bk_,dd[i][j],0,0,0);
      }
    float mt=-3.0e38f;
    #pragma unroll
    for(int i=0;i<2;i++)
      #pragma unroll
      for(int j=0;j<4;j++)
        #pragma unroll
        for(int r=0;r<4;r++) mt=fmaxf(mt,dd[i][j][r]);
    #pragma unroll
    for(int m=1;m<64;m<<=1) mt=fmaxf(mt,__shfl_xor(mt,m));
    if(mt>m_run){
      float sc=__expf(m_run-mt);
      #pragma unroll
      for(int i=0;i<2;i++)
        #pragma unroll
        for(int j2=0;j2<5;j2++) ctx[i][j2]*=sc;
      m_run=mt;
    }
    #pragma unroll
    for(int j=0;j<4;j++){
      const float dgn=dgl[j*16+(ln&15)];
      #pragma unroll
      for(int i=0;i<2;i++)
        #pragma unroll
        for(int r=0;r<4;r++){
          int m_l=wv*32+i*16+(ln>>4)*4+r;
          float E=__expf(dd[i][j][r]-dgn-m_run);
          kp_l[m_l*64 + (((j*2+((ln>>3)&1))^(m_l&7))<<3) + (ln&7)]=f2bf(E);
        }
    }
    #pragma unroll
    for(int tk=0;tk<2;tk++){
      short8 af2[2];
      #pragma unroll
      for(int i=0;i<2;i++)
        af2[i]=*(const short8*)&kp_l[(wv*32+i*16+(ln&15))*64 + (((tk*4+(ln>>4))^(ln&7))<<3)];
      #pragma unroll
      for(int j2=0;j2<5;j2++){
        short8 bf2=*(const short8*)&vl[(j2*16+(ln&15))*64 + (((tk*4+(ln>>4))^(ln&7))<<3)];
        #pragma unroll
        for(int i=0;i<2;i++)
          ctx[i][j2]=__builtin_amdgcn_mfma_f32_16x16x32_bf16(af2[i],bf2,ctx[i][j2],0,0,0);
      }
    }
    __syncthreads();
  }
  float* po=part + ((size_t)(bh*NCHUNK+kc))*(256*80);
  #pragma unroll
  for(int i=0;i<2;i++)
    #pragma unroll
    for(int j2=0;j2<5;j2++)
      #pragma unroll
      for(int r=0;r<4;r++)
        po[(size_t)(wv*32+i*16+(ln>>4)*4+r)*80 + j2*16+(ln&15)]=ctx[i][j2][r];
  if(ln==0) maxb[bh*64 + kc*8 + wv]=m_run;
}

// ---------------- ctx reduce: rescale chunk partials + analytic eps ----------------
__global__ __launch_bounds__(256) void ctx_reduce(const float* __restrict__ part, const float* __restrict__ maxb,
                                                  const float* __restrict__ vs,
                                                  u16* __restrict__ ctxT, float* __restrict__ ksum){
  __shared__ float mx_s[64];
  __shared__ float sc_s[NCHUNK];
  const int mseg=blockIdx.x, bh=blockIdx.y, tid=threadIdx.x;
  if(tid<64) mx_s[tid]=maxb[(size_t)bh*64+tid];
  __syncthreads();
  float km=-3.0e38f;
  for(int i=0;i<64;i++) km=fmaxf(km,mx_s[i]);
  const int m0=mseg*32;      // wave index that owned these rows == mseg
  if(tid<NCHUNK) sc_s[tid]=__expf(mx_s[tid*8+mseg]-km);
  __syncthreads();
  for(int rep=0;rep<10;rep++){
    int idx=rep*256+tid;           // 0..2559 = 32*80
    int mo=idx/80, d=idx-mo*80;
    int m=m0+mo;
    float s=0;
    #pragma unroll
    for(int c=0;c<NCHUNK;c++)
      s+=sc_s[c]*part[((size_t)(bh*NCHUNK+c))*(256*80) + (size_t)m*80 + d];
    float vsd=(d<=64)? vs[bh*80+d] : 0.0f;
    float val=0.0625f*(s + 1e-4f*vsd);
    if(d<64)       ctxT[((size_t)bh*64+d)*NBFX + m]=f2bf(val);
    else if(d==64) ksum[bh*NBFX+m]=val;
  }
}

// ---------------- column sums of ctxT / ksum ----------------
__global__ void csum_k(const u16* __restrict__ ctxT, const float* __restrict__ ksum, float* __restrict__ cs){
  const int bh=blockIdx.x, t=threadIdx.x;
  if(t<64){
    const u16* r=ctxT+((size_t)bh*64+t)*NBFX;
    float s=0;
    for(int m=0;m<NBFX;m+=8){
      short8 v=*(const short8*)&r[m];
      #pragma unroll
      for(int e=0;e<8;e++) s+=bf2f((u16)v[e]);
    }
    cs[bh*80+t]=s;
  } else if(t==64){
    float s=0;
    for(int m=0;m<NBFX;m++) s+=ksum[bh*NBFX+m];
    cs[bh*80+64]=s;
  }
}

// ---------------- fused query path (no-max E-form) ----------------
__global__ __launch_bounds__(256) void q_fused(const u16* __restrict__ qb, const u16* __restrict__ pj,
                                               const u16* __restrict__ ctxT, const float* __restrict__ ksum,
                                               const float* __restrict__ cs, u16* __restrict__ ob){
  __shared__ u16 ql[64*64];
  __shared__ u16 qpl[64*136];
  __shared__ float dgs[64];
  __shared__ float mred[4*64], dred[4*64];
  __shared__ float ff_s[64], dinv_s[64];
  const int bh=blockIdx.y, b_=bh>>3, h_=bh&7;
  const int n0=blockIdx.x*64;
  const int tid=threadIdx.x, wv=tid>>6, ln=tid&63;
  const u16* qg=qb+((size_t)(b_*SEQ+n0))*DIMX + h_*DHEAD;
  #pragma unroll
  for(int cc=0;cc<2;cc++){
    int c=cc*256+wv*64+ln; int t=c>>3, g=c&7;
    gload16(qg+(size_t)t*DIMX+((g^(t&7))*8), &ql[(size_t)(cc*256+wv*64)*8]);
  }
  short8 pjf[2][2][2];
  float ks[2][2][4];
  #pragma unroll
  for(int h=0;h<2;h++)
    #pragma unroll
    for(int i=0;i<2;i++){
      #pragma unroll
      for(int t=0;t<2;t++)
        pjf[h][i][t]=*(const short8*)&pj[(size_t)(h*128+wv*32+i*16+(ln&15))*DHEAD + t*32 + (ln>>4)*8];
      #pragma unroll
      for(int r=0;r<4;r++)
        ks[h][i][r]=ksum[bh*NBFX + h*128+wv*32+i*16+(ln>>4)*4+r];
    }
  const float KS=cs[bh*80+64];
  __syncthreads();
  if(tid<64){
    float ss=0;
    #pragma unroll
    for(int gg=0;gg<8;gg++){
      short8 kv=*(const short8*)&ql[tid*64 + ((gg+tid)&7)*8];
      #pragma unroll
      for(int e=0;e<8;e++){ float x=bf2f((u16)kv[e]); ss+=x*x; }
    }
    dgs[tid]=ss*0.0625f;
  }
  __syncthreads();
  float mxp[4]={-3.0e38f,-3.0e38f,-3.0e38f,-3.0e38f};
  float dnp[4]={0,0,0,0};
  f32x4 oc[4]={};
  const u16* cb=ctxT+(size_t)bh*64*NBFX;
  #pragma unroll
  for(int h=0;h<2;h++){
    #pragma unroll
    for(int j=0;j<4;j++){
      f32x4 dq[2]={};
      #pragma unroll
      for(int tk=0;tk<2;tk++){
        short8 bq=*(const short8*)&ql[(j*16+(ln&15))*64 + (((tk*4+(ln>>4))^(ln&7))<<3)];
        #pragma unroll
        for(int i=0;i<2;i++)
          dq[i]=__builtin_amdgcn_mfma_f32_16x16x32_bf16(pjf[h][i][tk],bq,dq[i],0,0,0);
      }
      const float dgn=dgs[j*16+(ln&15)];
      #pragma unroll
      for(int i=0;i<2;i++)
        #pragma unroll
        for(int r=0;r<4;r++){
          float d_=dq[i][r];
          mxp[j]=fmaxf(mxp[j],d_);
          float E=__expf(d_-dgn);
          dnp[j]+=E*ks[h][i][r];
          qpl[(j*16+(ln&15))*136 + wv*32+i*16+(ln>>4)*4+r]=f2bf(E);
        }
    }
    __syncthreads();
    #pragma unroll
    for(int mk2=0;mk2<4;mk2++){
      short8 aq=*(const short8*)&cb[(size_t)(wv*16+(ln&15))*NBFX + h*128 + mk2*32 + (ln>>4)*8];
      #pragma unroll
      for(int j2=0;j2<4;j2++){
        short8 bqp=*(const short8*)&qpl[(j2*16+(ln&15))*136 + mk2*32 + (ln>>4)*8];
        oc[j2]=__builtin_amdgcn_mfma_f32_16x16x32_bf16(aq,bqp,oc[j2],0,0,0);
      }
    }
    __syncthreads();
  }
  #pragma unroll
  for(int j=0;j<4;j++){
    #pragma unroll
    for(int msk=16;msk<64;msk<<=1){
      mxp[j]=fmaxf(mxp[j],__shfl_xor(mxp[j],msk));
      dnp[j]+=__shfl_xor(dnp[j],msk);
    }
  }
  if(ln<16){
    #pragma unroll
    for(int j=0;j<4;j++){ mred[wv*64+j*16+ln]=mxp[j]; dred[wv*64+j*16+ln]=dnp[j]; }
  }
  __syncthreads();
  if(tid<64){
    float mx=fmaxf(fmaxf(mred[tid],mred[64+tid]),fmaxf(mred[128+tid],mred[192+tid]));
    float dn=dred[tid]+dred[64+tid]+dred[128+tid]+dred[192+tid];
    float f=1e-4f*__expf(mx);
    ff_s[tid]=f;
    dinv_s[tid]=1.0f/(dn + f*KS);
  }
  __syncthreads();
  float csr[4];
  #pragma unroll
  for(int r=0;r<4;r++) csr[r]=cs[bh*80 + wv*16+(ln>>4)*4+r];
  u16* og=ob+((size_t)(b_*SEQ+n0))*DIMX + h_*DHEAD;
  #pragma unroll
  for(int j2=0;j2<4;j2++){
    int n=j2*16+(ln&15);
    float f=ff_s[n], di=dinv_s[n];
    u16 pk[4];
    #pragma unroll
    for(int r=0;r<4;r++) pk[r]=f2bf((oc[j2][r]+f*csr[r])*di);
    uint2 pv; pv.x=(unsigned)pk[0]|((unsigned)pk[1]<<16); pv.y=(unsigned)pk[2]|((unsigned)pk[3]<<16);
    *(uint2*)&og[(size_t)n*DIMX + wv*16+(ln>>4)*4]=pv;
  }
}

// ---------------- workspace layout (~204 MiB) ----------------
static constexpr size_t SZ_ACT=(size_t)TOK*DIMX*2;                 // 32 MiB
static constexpr size_t O_X=0;                                     // bf16 trunk
static constexpr size_t O_Y=SZ_ACT, O_Q=2*SZ_ACT, O_K=3*SZ_ACT;
static constexpr size_t O_VT=4*SZ_ACT;                             // 128 MiB
static constexpr size_t SZ_VT=(size_t)NBH*VROWS*SEQ*2;             // 40 MiB
static constexpr size_t O_PART=O_VT+SZ_VT;                         // 168 MiB
static constexpr size_t SZ_PART=(size_t)NBH*NCHUNK*256*80*4;       // 20 MiB
static constexpr size_t O_CTXT=O_PART+SZ_PART;
static constexpr size_t SZ_CTXT=(size_t)NBH*64*NBFX*2;
static constexpr size_t O_KSUM=O_CTXT+SZ_CTXT;
static constexpr size_t SZ_KSUM=(size_t)NBH*NBFX*4;
static constexpr size_t O_MAX=O_KSUM+SZ_KSUM;
static constexpr size_t SZ_MAX=(size_t)NBH*64*4;
static constexpr size_t O_VSUM=O_MAX+SZ_MAX;
static constexpr size_t SZ_VSUM=(size_t)NBH*80*4;
static constexpr size_t O_CS=O_VSUM+SZ_VSUM;
static constexpr size_t SZ_CS=(size_t)NBH*80*4;
static constexpr size_t O_WQKV=(size_t)192*1024*1024;
static_assert(O_CS+SZ_CS <= O_WQKV, "small buffers must end below weight region");
static constexpr size_t SZ_WQKV=(size_t)2*1536*DIMX*2;             // 3 MiB
static constexpr size_t O_WOT=O_WQKV+SZ_WQKV;
static constexpr size_t SZ_W=(size_t)2*DIMX*DIMX*2;                // 1 MiB
static constexpr size_t O_W1T=O_WOT+SZ_W;
static constexpr size_t SZ_W1=(size_t)2*FFD*DIMX*2;                // 4 MiB
static constexpr size_t O_W2T=O_W1T+SZ_W1;
static constexpr size_t O_PJ=O_W2T+SZ_W1;
static constexpr size_t O_QKVB=O_PJ+(size_t)2*NBFX*DHEAD*2;
static constexpr size_t WS_END=O_QKVB+(size_t)2*1536*4;

extern "C" void kernel_launch(void* const* d_in, const int* in_sizes, int n_in,
                              void* d_out, int out_size, void* d_ws, size_t ws_size,
                              hipStream_t stream){
  (void)in_sizes;(void)n_in;(void)out_size;
  const float* xin =(const float*)d_in[0];
  const float* ln1g=(const float*)d_in[1];
  const float* ln1b=(const float*)d_in[2];
  const float* ln2g=(const float*)d_in[3];
  const float* ln2b=(const float*)d_in[4];
  const float* Wq=(const float*)d_in[5];
  const float* bq=(const float*)d_in[6];
  const float* Wk=(const float*)d_in[7];
  const float* bk=(const float*)d_in[8];
  const float* Wv=(const float*)d_in[9];
  const float* bv=(const float*)d_in[10];
  const float* Wo=(const float*)d_in[11];
  const float* bo=(const float*)d_in[12];
  const float* proj=(const float*)d_in[13];
  const float* W1=(const float*)d_in[14];
  const float* b1=(const float*)d_in[15];
  const float* W2=(const float*)d_in[16];
  const float* b2=(const float*)d_in[17];
  float* xout=(float*)d_out;

  if(ws_size < WS_END){
    copy_f32<<<(TOK*DIMX/4)/256,256,0,stream>>>((const float4*)xin,(float4*)xout, TOK*DIMX/4);
    return;
  }

  char* ws=(char*)d_ws;
  u16* xtr  =(u16*)(ws+O_X);      // bf16 residual trunk
  u16* ybuf =(u16*)(ws+O_Y);
  u16* qbuf =(u16*)(ws+O_Q);
  u16* kbuf =(u16*)(ws+O_K);
  u16* vtb  =(u16*)(ws+O_VT);
  float* partb=(float*)(ws+O_PART);
  u16* ctxtb=(u16*)(ws+O_CTXT);
  float* ksumb=(float*)(ws+O_KSUM);
  float* maxb=(float*)(ws+O_MAX);
  float* vsumb=(float*)(ws+O_VSUM);
  float* csb=(float*)(ws+O_CS);
  u16* wqkvt=(u16*)(ws+O_WQKV);
  u16* wot=(u16*)(ws+O_WOT);
  u16* w1t=(u16*)(ws+O_W1T); u16* w2t=(u16*)(ws+O_W2T);
  u16* pjb=(u16*)(ws+O_PJ);
  float* qkvb=(float*)(ws+O_QKVB);
  u16* hbuf=(u16*)(ws+O_Q);   // FF hidden [32768][2048] overlays q/k/vt/part/small regions

  for(int l=0;l<2;l++){
    size_t wo=(size_t)l*DIMX*DIMX;
    convT<<<dim3(16,16),dim3(32,8),0,stream>>>(Wq+wo, wqkvt+(size_t)(l*1536+   0)*DIMX, DIMX, DIMX);
    convT<<<dim3(16,16),dim3(32,8),0,stream>>>(Wk+wo, wqkvt+(size_t)(l*1536+ 512)*DIMX, DIMX, DIMX);
    convT<<<dim3(16,16),dim3(32,8),0,stream>>>(Wv+wo, wqkvt+(size_t)(l*1536+1024)*DIMX, DIMX, DIMX);
    convT<<<dim3(16,16),dim3(32,8),0,stream>>>(Wo+wo, wot+wo, DIMX, DIMX);
    size_t w1o=(size_t)l*DIMX*FFD;
    convT<<<dim3(64,16),dim3(32,8),0,stream>>>(W1+w1o, w1t+w1o, DIMX, FFD);
    convT<<<dim3(16,64),dim3(32,8),0,stream>>>(W2+w1o, w2t+w1o, FFD, DIMX);
  }
  conv_proj<<<(2*NBFX*DHEAD)/256,256,0,stream>>>(proj, pjb, 2*NBFX*DHEAD);
  pack_bias<<<12,256,0,stream>>>(bq,bk,bv,qkvb);

  for(int l=0;l<2;l++){
    const u16* wqkvt_l=wqkvt+(size_t)l*1536*DIMX;
    const u16* wot_l=wot+(size_t)l*DIMX*DIMX;
    const u16* w1t_l=w1t+(size_t)l*DIMX*FFD;
    const u16* w2t_l=w2t+(size_t)l*DIMX*FFD;
    const u16* pj_l =pjb+(size_t)l*NBFX*DHEAD;
    const float* qkvb_l=qkvb+(size_t)l*1536;

    if(l==0) ln_f32<<<TOK/4,256,0,stream>>>(xin, ln1g, ln1b, ybuf);
    else     ln_k<<<TOK/4,256,0,stream>>>(xtr, ln1g+l*DIMX, ln1b+l*DIMX, ybuf);
    fill_vt<<<(NBH*16*SEQ)/256,256,0,stream>>>(vtb);
    gemm256<0,512><<<dim3(6,128),512,0,stream>>>(ybuf, wqkvt_l, qkvb_l, qbuf, vtb, nullptr, 1536);
    vsum_k<<<520,256,0,stream>>>(vtb, vsumb);
    kctx<<<dim3(NCHUNK,32),512,0,stream>>>(kbuf, pj_l, vtb, partb, maxb);
    ctx_reduce<<<dim3(8,32),256,0,stream>>>(partb, maxb, vsumb, ctxtb, ksumb);
    csum_k<<<32,256,0,stream>>>(ctxtb, ksumb, csb);
    q_fused<<<dim3(128,32),256,0,stream>>>(qbuf, pj_l, ctxtb, ksumb, csb, ybuf);
    if(l==0) gemm256<3,512><<<dim3(2,128),512,0,stream>>>(ybuf, wot_l, bo, xtr, nullptr, xin, DIMX);
    else     gemm256<1,512><<<dim3(2,128),512,0,stream>>>(ybuf, wot_l, bo+l*DIMX, xtr, nullptr, nullptr, DIMX);
    ln_k<<<TOK/4,256,0,stream>>>(xtr, ln2g+l*DIMX, ln2b+l*DIMX, ybuf);
    gemm256<2,512><<<dim3(8,128),512,0,stream>>>(ybuf, w1t_l, b1+l*FFD, hbuf, nullptr, nullptr, FFD);
    if(l==0) gemm256<1,2048><<<dim3(2,128),512,0,stream>>>(hbuf, w2t_l, b2, xtr, nullptr, nullptr, DIMX);
    else     gemm256<4,2048><<<dim3(2,128),512,0,stream>>>(hbuf, w2t_l, b2+l*DIMX, xout, nullptr, xtr, DIMX);
  }
}

// Round 15
// 967.388 us; speedup vs baseline: 1.1546x; 1.1546x over previous
//
#include <hip/hip_runtime.h>
#include <math.h>

#define DIMX 512
#define HEADS 8
#define DHEAD 64
#define NBFX 256
#define FFD 2048
#define NBX 4
#define SEQ 8192
#define TOK (NBX*SEQ)     // 32768 tokens
#define NBH (NBX*HEADS)   // 32 (b,h) pairs
#define VROWS 80          // 64 v-dims + ones row(64) + zeros pad
#define NCHUNK 8          // ctx K-split chunks (1024 tokens each)
#define BK 64

typedef unsigned short u16;
typedef __attribute__((ext_vector_type(8))) short short8;
typedef __attribute__((ext_vector_type(4))) float f32x4;

__device__ __forceinline__ float bf2f(u16 x){ return __uint_as_float(((unsigned)x)<<16); }
__device__ __forceinline__ u16 f2bf(float f){
  unsigned u=__float_as_uint(f);
  return (u16)((u + 0x7FFFu + ((u>>16)&1u))>>16);
}
__device__ __forceinline__ void gload16(const void* g, void* l){
  __builtin_amdgcn_global_load_lds((const __attribute__((address_space(1))) void*)g,
                                   (__attribute__((address_space(3))) void*)l, 16, 0, 0);
}
// exact-GELU via A&S 7.1.26 erf approx (max erf err 1.5e-7)
__device__ __forceinline__ float gelu_f(float v){
  float x=v*0.70710678118654752f;
  float ax=fabsf(x);
  float t=1.0f/(1.0f+0.3275911f*ax);
  float p=t*(0.254829592f+t*(-0.284496736f+t*(1.421413741f+t*(-1.453152027f+t*1.061405429f))));
  float erfv=1.0f-p*__expf(-ax*ax);
  erfv=(x<0.0f)? -erfv : erfv;
  return 0.5f*v*(1.0f+erfv);
}

#define FENCE asm volatile(""::: "memory")
#define BAR() do{ FENCE; __builtin_amdgcn_s_barrier(); FENCE; }while(0)

// ---------------- prep / elementwise ----------------
__global__ void copy_f32(const float4* __restrict__ s, float4* __restrict__ d, int n4){
  int i=blockIdx.x*blockDim.x+threadIdx.x;
  if(i<n4) d[i]=s[i];
}
__global__ void conv_proj(const float* __restrict__ p, u16* __restrict__ o, int n){
  int i=blockIdx.x*blockDim.x+threadIdx.x;
  if(i<n) o[i]=f2bf(p[i]*0.35355339059327373f); // fold d^-0.25 into proj
}
// src fp32 [K][Ncol] -> dst bf16 [Ncol][K] (transposed)
__global__ void convT(const float* __restrict__ src, u16* __restrict__ dst, int K, int Ncol){
  __shared__ float t[32][33];
  int k0=blockIdx.y*32, n0=blockIdx.x*32;
  int tx=threadIdx.x, ty=threadIdx.y;
  for(int i=ty;i<32;i+=8) t[i][tx]=src[(size_t)(k0+i)*Ncol + n0+tx];
  __syncthreads();
  for(int i=ty;i<32;i+=8) dst[(size_t)(n0+i)*K + k0+tx]=f2bf(t[tx][i]);
}
__global__ void fill_vt(u16* __restrict__ vt){
  int i=blockIdx.x*blockDim.x+threadIdx.x; // < NBH*16*SEQ = 2^22
  int n=i&(SEQ-1); int r=(i>>13)&15; int bh=i>>17;
  vt[((size_t)bh*VROWS + 64 + r)*SEQ + n] = (r==0)? (u16)0x3F80 : (u16)0;
}
__global__ void pack_bias(const float* __restrict__ bq, const float* __restrict__ bk,
                          const float* __restrict__ bv, float* __restrict__ o){
  int i=blockIdx.x*blockDim.x+threadIdx.x; // 2*1536
  int l=i/1536, c=i-l*1536;
  const float* s=(c<512)? bq : ((c<1024)? bk : bv);
  o[i]=s[l*512 + (c&511)];
}

// wave-per-row LN over bf16 trunk
__global__ __launch_bounds__(256) void ln_k(const u16* __restrict__ x, const float* __restrict__ g,
                                            const float* __restrict__ b, u16* __restrict__ y){
  const int row=blockIdx.x*4 + (threadIdx.x>>6);
  const int ln=threadIdx.x&63;
  const u16* xr=x+(size_t)row*DIMX;
  short8 xv=*(const short8*)(xr+ln*8);
  float v[8];
  #pragma unroll
  for(int e=0;e<8;e++) v[e]=bf2f((u16)xv[e]);
  float s=0;
  #pragma unroll
  for(int e=0;e<8;e++) s+=v[e];
  #pragma unroll
  for(int m=1;m<64;m<<=1) s+=__shfl_xor(s,m);
  const float mean=s*(1.0f/DIMX);
  float s2=0;
  #pragma unroll
  for(int e=0;e<8;e++){ v[e]-=mean; s2+=v[e]*v[e]; }
  #pragma unroll
  for(int m=1;m<64;m<<=1) s2+=__shfl_xor(s2,m);
  const float rs=rsqrtf(s2*(1.0f/DIMX)+1e-5f);
  u16* yr=y+(size_t)row*DIMX+ln*8;
  u16 pk[8];
  #pragma unroll
  for(int e=0;e<8;e++) pk[e]=f2bf(v[e]*rs*g[ln*8+e]+b[ln*8+e]);
  uint4 pv;
  pv.x=(unsigned)pk[0]|((unsigned)pk[1]<<16); pv.y=(unsigned)pk[2]|((unsigned)pk[3]<<16);
  pv.z=(unsigned)pk[4]|((unsigned)pk[5]<<16); pv.w=(unsigned)pk[6]|((unsigned)pk[7]<<16);
  *(uint4*)yr=pv;
}
// wave-per-row LN over fp32 input (layer-0 entry)
__global__ __launch_bounds__(256) void ln_f32(const float* __restrict__ x, const float* __restrict__ g,
                                              const float* __restrict__ b, u16* __restrict__ y){
  const int row=blockIdx.x*4 + (threadIdx.x>>6);
  const int ln=threadIdx.x&63;
  const float* xr=x+(size_t)row*DIMX;
  float4 v0=*(const float4*)&xr[ln*8];
  float4 v1=*(const float4*)&xr[ln*8+4];
  float v[8]={v0.x,v0.y,v0.z,v0.w,v1.x,v1.y,v1.z,v1.w};
  float s=0;
  #pragma unroll
  for(int e=0;e<8;e++) s+=v[e];
  #pragma unroll
  for(int m=1;m<64;m<<=1) s+=__shfl_xor(s,m);
  const float mean=s*(1.0f/DIMX);
  float s2=0;
  #pragma unroll
  for(int e=0;e<8;e++){ v[e]-=mean; s2+=v[e]*v[e]; }
  #pragma unroll
  for(int m=1;m<64;m<<=1) s2+=__shfl_xor(s2,m);
  const float rs=rsqrtf(s2*(1.0f/DIMX)+1e-5f);
  u16* yr=y+(size_t)row*DIMX+ln*8;
  u16 pk[8];
  #pragma unroll
  for(int e=0;e<8;e++) pk[e]=f2bf(v[e]*rs*g[ln*8+e]+b[ln*8+e]);
  uint4 pv;
  pv.x=(unsigned)pk[0]|((unsigned)pk[1]<<16); pv.y=(unsigned)pk[2]|((unsigned)pk[3]<<16);
  pv.z=(unsigned)pk[4]|((unsigned)pk[5]<<16); pv.w=(unsigned)pk[6]|((unsigned)pk[7]<<16);
  *(uint4*)yr=pv;
}

// ---------------- 256x256 8-phase pipelined bf16 GEMM ----------------
// EPI 0: QKV (q/k bf16 + vT); 1: bf16 trunk +=; 2: gelu->bf16;
// 3: bf16_out = f2bf(aux_f32 + acc + b); 4: f32_out = bf2f(aux_bf16) + acc + b
#define MFMA16(MH,BF,NH) do{                                                             \
  __builtin_amdgcn_s_setprio(1);                                                         \
  _Pragma("unroll") for(int kk_=0;kk_<2;kk_++)                                           \
    _Pragma("unroll") for(int i_=0;i_<4;i_++)                                            \
      _Pragma("unroll") for(int j_=0;j_<2;j_++)                                          \
        acc[MH][i_][NH][j_]=__builtin_amdgcn_mfma_f32_16x16x32_bf16(af[i_][kk_],BF[j_][kk_],acc[MH][i_][NH][j_],0,0,0); \
  __builtin_amdgcn_s_setprio(0);                                                         \
}while(0)

#define STG(T,HALF,ISB,BUF) do{ if((T)<nt){                                              \
  gload16(gp[ISB][HALF][0]+(size_t)(T)*BK, &lds[BUF][ISB][(HALF)*128 +    wv*8][0]);     \
  gload16(gp[ISB][HALF][1]+(size_t)(T)*BK, &lds[BUF][ISB][(HALF)*128 + 64+wv*8][0]); } }while(0)

#define LDA(BUF,MH) do{                                                                  \
  _Pragma("unroll") for(int i_=0;i_<4;i_++)                                              \
    _Pragma("unroll") for(int kk_=0;kk_<2;kk_++)                                         \
      af[i_][kk_]=*(const short8*)((const u16*)lds[BUF][0] + aoffs[MH][i_][kk_]); }while(0)

#define LDB(BF,BUF,NH) do{                                                               \
  _Pragma("unroll") for(int j_=0;j_<2;j_++)                                              \
    _Pragma("unroll") for(int kk_=0;kk_<2;kk_++)                                         \
      BF[j_][kk_]=*(const short8*)((const u16*)lds[BUF][1] + boffs[NH][j_][kk_]); }while(0)

#define TILE(T,BUF,OBUF) do{                                                             \
  LDB(bf0,BUF,0); LDA(BUF,0);                                                            \
  STG((T)+1,1,0,OBUF);                                                                   \
  BAR(); MFMA16(0,bf0,0); BAR();                                                         \
  LDB(bf1,BUF,1);                                                                        \
  STG((T)+1,1,1,OBUF);                                                                   \
  BAR(); MFMA16(0,bf1,1); BAR();                                                         \
  LDA(BUF,1);                                                                            \
  STG((T)+2,0,1,BUF);                                                                    \
  BAR(); MFMA16(1,bf0,0); BAR();                                                         \
  STG((T)+2,0,0,BUF);                                                                    \
  BAR(); MFMA16(1,bf1,1);                                                                \
  if((T)+2<nt) asm volatile("s_waitcnt vmcnt(4)":::"memory");                            \
  else         asm volatile("s_waitcnt vmcnt(0)":::"memory");                            \
  BAR();                                                                                 \
}while(0)

template<int EPI,int K>
__global__ __launch_bounds__(512,2) void gemm256(const u16* __restrict__ A, const u16* __restrict__ Bt,
                                                 const float* __restrict__ bias, void* __restrict__ outp,
                                                 u16* __restrict__ out2, const void* __restrict__ aux,
                                                 int Ncol){
  constexpr int nt=K/BK;
  constexpr int HS=(K==2048)?1:2;       // band height log2
  constexpr int H=1<<HS;
  __shared__ u16 lds[2][2][256][64];
  const int tid=threadIdx.x, wv=tid>>6, ln=tid&63;
  const int wr=wv>>2, wc=wv&3;
  const int gx=gridDim.x;
  const int P=blockIdx.y*gx+blockIdx.x;
  const int grp=8*H*gx;
  const int G=P/grp, R=P-G*grp;
  const int xcd=R&7, s=R>>3;
  const int by=(G*8+xcd)*H + (s&(H-1));
  const int bx=s>>HS;
  const int m0=by*256, n0=bx*256;
  f32x4 acc[2][4][2][2]={};

  const u16* gp[2][2][2];
  #pragma unroll
  for(int isB=0;isB<2;isB++)
    #pragma unroll
    for(int half=0;half<2;half++)
      #pragma unroll
      for(int ss=0;ss<2;ss++){
        int Gg=ss*512+wv*64+ln;
        int arow=half*128+(Gg>>3), g=Gg&7;
        const u16* src=isB? Bt:A;
        int b0=isB? n0:m0;
        gp[isB][half][ss]=src+(size_t)(b0+arow)*K+((g^(arow&7))<<3);
      }
  int aoffs[2][4][2], boffs[2][2][2];
  #pragma unroll
  for(int mh=0;mh<2;mh++)
    #pragma unroll
    for(int i=0;i<4;i++){
      int row=wr*128+mh*64+i*16+(ln&15);
      #pragma unroll
      for(int kk=0;kk<2;kk++)
        aoffs[mh][i][kk]=row*64+((((kk*4+(ln>>4)))^(row&7))<<3);
    }
  #pragma unroll
  for(int nh=0;nh<2;nh++)
    #pragma unroll
    for(int j=0;j<2;j++){
      int row=wc*64+nh*32+j*16+(ln&15);
      #pragma unroll
      for(int kk=0;kk<2;kk++)
        boffs[nh][j][kk]=row*64+((((kk*4+(ln>>4)))^(row&7))<<3);
    }

  short8 af[4][2], bf0[2][2], bf1[2][2];

  STG(0,0,0,0); STG(0,1,0,0); STG(0,0,1,0); STG(0,1,1,0);
  STG(1,0,1,1); STG(1,0,0,1);
  asm volatile("s_waitcnt vmcnt(4)":::"memory");
  BAR();

  #pragma unroll 1
  for(int t=0;t<nt;t+=2){
    TILE(t,0,1);
    TILE(t+1,1,0);
  }

  // epilogue
  #pragma unroll
  for(int mh=0;mh<2;mh++)
  #pragma unroll
  for(int i=0;i<4;i++)
  #pragma unroll
  for(int nh=0;nh<2;nh++)
  #pragma unroll
  for(int j=0;j<2;j++){
    const int row=m0+wr*128+mh*64+i*16+(ln>>4)*4;
    const int col=n0+wc*64+nh*32+j*16+(ln&15);
    const float bv=bias[col];
    const f32x4 a=acc[mh][i][nh][j];
    if constexpr(EPI==0){
      if(col<1024){
        u16* o=(u16*)outp + (size_t)(col>>9)*TOK*DIMX + (col&511);
        #pragma unroll
        for(int r=0;r<4;r++) o[(size_t)(row+r)*DIMX]=f2bf(a[r]+bv);
      } else {
        const int hd=col-1024, h_=hd>>6, d_=hd&63, b_=row>>13, nn=row&(SEQ-1);
        u16 pk[4];
        #pragma unroll
        for(int r=0;r<4;r++) pk[r]=f2bf(a[r]+bv);
        uint2 pv; pv.x=(unsigned)pk[0]|((unsigned)pk[1]<<16); pv.y=(unsigned)pk[2]|((unsigned)pk[3]<<16);
        *(uint2*)&out2[((size_t)(b_*HEADS+h_)*VROWS+d_)*SEQ+nn]=pv;
      }
    } else if constexpr(EPI==1){ // bf16 trunk residual RMW
      u16* o=(u16*)outp;
      #pragma unroll
      for(int r=0;r<4;r++){
        size_t ix=(size_t)(row+r)*Ncol+col;
        o[ix]=f2bf(bf2f(o[ix])+a[r]+bv);
      }
    } else if constexpr(EPI==2){
      u16* o=(u16*)outp;
      #pragma unroll
      for(int r=0;r<4;r++)
        o[(size_t)(row+r)*Ncol+col]=f2bf(gelu_f(a[r]+bv));
    } else if constexpr(EPI==3){ // bf16 trunk = fp32 aux + acc + b
      u16* o=(u16*)outp;
      const float* ax=(const float*)aux;
      #pragma unroll
      for(int r=0;r<4;r++){
        size_t ix=(size_t)(row+r)*Ncol+col;
        o[ix]=f2bf(ax[ix]+a[r]+bv);
      }
    } else { // EPI==4: fp32 out = bf16 aux + acc + b
      float* o=(float*)outp;
      const u16* ax=(const u16*)aux;
      #pragma unroll
      for(int r=0;r<4;r++){
        size_t ix=(size_t)(row+r)*Ncol+col;
        o[ix]=bf2f(ax[ix])+a[r]+bv;
      }
    }
  }
}

// ---------------- vsum: per (bh,d<=64) row-sum of vT over all n ----------------
__global__ __launch_bounds__(256) void vsum_k(const u16* __restrict__ vt, float* __restrict__ vs){
  const int gw=blockIdx.x*4 + (threadIdx.x>>6); // 0..2079 = 32*65
  const int ln=threadIdx.x&63;
  const int bh=gw/65, d=gw-bh*65;
  const u16* row=vt+((size_t)bh*VROWS+d)*SEQ;
  float s=0;
  for(int it=0;it<16;it++){
    short8 v=*(const short8*)&row[it*512+ln*8];
    #pragma unroll
    for(int e=0;e<8;e++) s+=bf2f((u16)v[e]);
  }
  #pragma unroll
  for(int m=1;m<64;m<<=1) s+=__shfl_xor(s,m);
  if(ln==0) vs[bh*80+d]=s;
}

// ---------------- fused k-features + ctx partial GEMM (deferred max, 8 waves) ----------------
// grid (NCHUNK, 32 bh), 512 threads; wave wv owns m rows wv*32..+32; k/v staged ONCE per block.
__global__ __launch_bounds__(512) void kctx(const u16* __restrict__ kb, const u16* __restrict__ pj,
                                            const u16* __restrict__ vt,
                                            float* __restrict__ part, float* __restrict__ maxb){
  __shared__ u16 kl[64*64];     // [token][d], granule-swizzled by token&7
  __shared__ u16 vl[80*64];     // [d][n],     granule-swizzled by d&7
  __shared__ u16 kp_l[256*64];  // [m][n], granule-swizzled (per-wave rows)
  __shared__ float dgl[64];
  const int kc=blockIdx.x, bh=blockIdx.y, b_=bh>>3, h_=bh&7;
  const int tid=threadIdx.x, wv=tid>>6, ln=tid&63;
  short8 pjf[2][2];
  #pragma unroll
  for(int i=0;i<2;i++)
    #pragma unroll
    for(int t=0;t<2;t++)
      pjf[i][t]=*(const short8*)&pj[(size_t)(wv*32+i*16+(ln&15))*DHEAD + t*32 + (ln>>4)*8];
  f32x4 ctx[2][5]={};
  float m_run=-3.0e38f;
  const u16* vbh=vt+(size_t)bh*VROWS*SEQ;
  for(int s=0;s<16;s++){
    const int n0s=kc*1024+s*64;
    const u16* kg=kb+((size_t)(b_*SEQ+n0s))*DIMX + h_*DHEAD;
    { // kl: 512 granules, 1/thread
      int t=tid>>3, g=tid&7;
      gload16(kg+(size_t)t*DIMX+((g^(t&7))*8), &kl[(size_t)tid*8]);
    }
    { // vl rows 0..63: 1/thread
      int d=tid>>3, g=tid&7;
      gload16(vbh+(size_t)d*SEQ+n0s+((g^(d&7))*8), &vl[(size_t)tid*8]);
    }
    if(tid<128){ // vl rows 64..79
      int c=512+tid; int d=c>>3, g=c&7;
      gload16(vbh+(size_t)d*SEQ+n0s+((g^(d&7))*8), &vl[(size_t)c*8]);
    }
    __syncthreads();
    if(tid<64){
      float ss=0;
      #pragma unroll
      for(int gg=0;gg<8;gg++){
        short8 kv=*(const short8*)&kl[tid*64 + ((gg+tid)&7)*8];
        #pragma unroll
        for(int e=0;e<8;e++){ float x=bf2f((u16)kv[e]); ss+=x*x; }
      }
      dgl[tid]=ss*0.0625f; // 0.5 * d^-0.5
    }
    __syncthreads();
    f32x4 dd[2][4]={};
    #pragma unroll
    for(int tk=0;tk<2;tk++)
      #pragma unroll
      for(int j=0;j<4;j++){
        short8 bk_=*(const short8*)&kl[(j*16+(ln&15))*64 + (((tk*4+(ln>>4))^(ln&7))<<3)];
        #pragma unroll
        for(int i=0;i<2;i++)
          dd[i][j]=__builtin_amdgcn_mfma_f32_16x16x32_bf16(pjf[i][tk],bk_,dd[i][j],0,0,0);
      }
    float mt=-3.0e38f;
    #pragma unroll
    for(int i=0;i<2;i++)
      #pragma unroll
      for(int j=0;j<4;j++)
        #pragma unroll
        for(int r=0;r<4;r++) mt=fmaxf(mt,dd[i][j][r]);
    #pragma unroll
    for(int m=1;m<64;m<<=1) mt=fmaxf(mt,__shfl_xor(mt,m));
    if(mt>m_run){
      float sc=__expf(m_run-mt);
      #pragma unroll
      for(int i=0;i<2;i++)
        #pragma unroll
        for(int j2=0;j2<5;j2++) ctx[i][j2]*=sc;
      m_run=mt;
    }
    #pragma unroll
    for(int j=0;j<4;j++){
      const float dgn=dgl[j*16+(ln&15)];
      #pragma unroll
      for(int i=0;i<2;i++)
        #pragma unroll
        for(int r=0;r<4;r++){
          int m_l=wv*32+i*16+(ln>>4)*4+r;
          float E=__expf(dd[i][j][r]-dgn-m_run);
          kp_l[m_l*64 + (((j*2+((ln>>3)&1))^(m_l&7))<<3) + (ln&7)]=f2bf(E);
        }
    }
    #pragma unroll
    for(int tk=0;tk<2;tk++){
      short8 af2[2];
      #pragma unroll
      for(int i=0;i<2;i++)
        af2[i]=*(const short8*)&kp_l[(wv*32+i*16+(ln&15))*64 + (((tk*4+(ln>>4))^(ln&7))<<3)];
      #pragma unroll
      for(int j2=0;j2<5;j2++){
        short8 bf2=*(const short8*)&vl[(j2*16+(ln&15))*64 + (((tk*4+(ln>>4))^(ln&7))<<3)];
        #pragma unroll
        for(int i=0;i<2;i++)
          ctx[i][j2]=__builtin_amdgcn_mfma_f32_16x16x32_bf16(af2[i],bf2,ctx[i][j2],0,0,0);
      }
    }
    __syncthreads();
  }
  float* po=part + ((size_t)(bh*NCHUNK+kc))*(256*80);
  #pragma unroll
  for(int i=0;i<2;i++)
    #pragma unroll
    for(int j2=0;j2<5;j2++)
      #pragma unroll
      for(int r=0;r<4;r++)
        po[(size_t)(wv*32+i*16+(ln>>4)*4+r)*80 + j2*16+(ln&15)]=ctx[i][j2][r];
  if(ln==0) maxb[bh*64 + kc*8 + wv]=m_run;
}

// ---------------- ctx reduce: rescale chunk partials + analytic eps ----------------
__global__ __launch_bounds__(256) void ctx_reduce(const float* __restrict__ part, const float* __restrict__ maxb,
                                                  const float* __restrict__ vs,
                                                  u16* __restrict__ ctxT, float* __restrict__ ksum){
  __shared__ float mx_s[64];
  __shared__ float sc_s[NCHUNK];
  const int mseg=blockIdx.x, bh=blockIdx.y, tid=threadIdx.x;
  if(tid<64) mx_s[tid]=maxb[(size_t)bh*64+tid];
  __syncthreads();
  float km=-3.0e38f;
  for(int i=0;i<64;i++) km=fmaxf(km,mx_s[i]);
  const int m0=mseg*32;      // wave index that owned these rows == mseg
  if(tid<NCHUNK) sc_s[tid]=__expf(mx_s[tid*8+mseg]-km);
  __syncthreads();
  for(int rep=0;rep<10;rep++){
    int idx=rep*256+tid;           // 0..2559 = 32*80
    int mo=idx/80, d=idx-mo*80;
    int m=m0+mo;
    float s=0;
    #pragma unroll
    for(int c=0;c<NCHUNK;c++)
      s+=sc_s[c]*part[((size_t)(bh*NCHUNK+c))*(256*80) + (size_t)m*80 + d];
    float vsd=(d<=64)? vs[bh*80+d] : 0.0f;
    float val=0.0625f*(s + 1e-4f*vsd);
    if(d<64)       ctxT[((size_t)bh*64+d)*NBFX + m]=f2bf(val);
    else if(d==64) ksum[bh*NBFX+m]=val;
  }
}

// ---------------- column sums of ctxT / ksum ----------------
__global__ void csum_k(const u16* __restrict__ ctxT, const float* __restrict__ ksum, float* __restrict__ cs){
  const int bh=blockIdx.x, t=threadIdx.x;
  if(t<64){
    const u16* r=ctxT+((size_t)bh*64+t)*NBFX;
    float s=0;
    for(int m=0;m<NBFX;m+=8){
      short8 v=*(const short8*)&r[m];
      #pragma unroll
      for(int e=0;e<8;e++) s+=bf2f((u16)v[e]);
    }
    cs[bh*80+t]=s;
  } else if(t==64){
    float s=0;
    for(int m=0;m<NBFX;m++) s+=ksum[bh*NBFX+m];
    cs[bh*80+64]=s;
  }
}

// ---------------- fused query path (no-max E-form) ----------------
__global__ __launch_bounds__(256) void q_fused(const u16* __restrict__ qb, const u16* __restrict__ pj,
                                               const u16* __restrict__ ctxT, const float* __restrict__ ksum,
                                               const float* __restrict__ cs, u16* __restrict__ ob){
  __shared__ u16 ql[64*64];
  __shared__ u16 qpl[64*136];
  __shared__ float dgs[64];
  __shared__ float mred[4*64], dred[4*64];
  __shared__ float ff_s[64], dinv_s[64];
  const int bh=blockIdx.y, b_=bh>>3, h_=bh&7;
  const int n0=blockIdx.x*64;
  const int tid=threadIdx.x, wv=tid>>6, ln=tid&63;
  const u16* qg=qb+((size_t)(b_*SEQ+n0))*DIMX + h_*DHEAD;
  #pragma unroll
  for(int cc=0;cc<2;cc++){
    int c=cc*256+wv*64+ln; int t=c>>3, g=c&7;
    gload16(qg+(size_t)t*DIMX+((g^(t&7))*8), &ql[(size_t)(cc*256+wv*64)*8]);
  }
  short8 pjf[2][2][2];
  float ks[2][2][4];
  #pragma unroll
  for(int h=0;h<2;h++)
    #pragma unroll
    for(int i=0;i<2;i++){
      #pragma unroll
      for(int t=0;t<2;t++)
        pjf[h][i][t]=*(const short8*)&pj[(size_t)(h*128+wv*32+i*16+(ln&15))*DHEAD + t*32 + (ln>>4)*8];
      #pragma unroll
      for(int r=0;r<4;r++)
        ks[h][i][r]=ksum[bh*NBFX + h*128+wv*32+i*16+(ln>>4)*4+r];
    }
  const float KS=cs[bh*80+64];
  __syncthreads();
  if(tid<64){
    float ss=0;
    #pragma unroll
    for(int gg=0;gg<8;gg++){
      short8 kv=*(const short8*)&ql[tid*64 + ((gg+tid)&7)*8];
      #pragma unroll
      for(int e=0;e<8;e++){ float x=bf2f((u16)kv[e]); ss+=x*x; }
    }
    dgs[tid]=ss*0.0625f;
  }
  __syncthreads();
  float mxp[4]={-3.0e38f,-3.0e38f,-3.0e38f,-3.0e38f};
  float dnp[4]={0,0,0,0};
  f32x4 oc[4]={};
  const u16* cb=ctxT+(size_t)bh*64*NBFX;
  #pragma unroll
  for(int h=0;h<2;h++){
    #pragma unroll
    for(int j=0;j<4;j++){
      f32x4 dq[2]={};
      #pragma unroll
      for(int tk=0;tk<2;tk++){
        short8 bq=*(const short8*)&ql[(j*16+(ln&15))*64 + (((tk*4+(ln>>4))^(ln&7))<<3)];
        #pragma unroll
        for(int i=0;i<2;i++)
          dq[i]=__builtin_amdgcn_mfma_f32_16x16x32_bf16(pjf[h][i][tk],bq,dq[i],0,0,0);
      }
      const float dgn=dgs[j*16+(ln&15)];
      #pragma unroll
      for(int i=0;i<2;i++)
        #pragma unroll
        for(int r=0;r<4;r++){
          float d_=dq[i][r];
          mxp[j]=fmaxf(mxp[j],d_);
          float E=__expf(d_-dgn);
          dnp[j]+=E*ks[h][i][r];
          qpl[(j*16+(ln&15))*136 + wv*32+i*16+(ln>>4)*4+r]=f2bf(E);
        }
    }
    __syncthreads();
    #pragma unroll
    for(int mk2=0;mk2<4;mk2++){
      short8 aq=*(const short8*)&cb[(size_t)(wv*16+(ln&15))*NBFX + h*128 + mk2*32 + (ln>>4)*8];
      #pragma unroll
      for(int j2=0;j2<4;j2++){
        short8 bqp=*(const short8*)&qpl[(j2*16+(ln&15))*136 + mk2*32 + (ln>>4)*8];
        oc[j2]=__builtin_amdgcn_mfma_f32_16x16x32_bf16(aq,bqp,oc[j2],0,0,0);
      }
    }
    __syncthreads();
  }
  #pragma unroll
  for(int j=0;j<4;j++){
    #pragma unroll
    for(int msk=16;msk<64;msk<<=1){
      mxp[j]=fmaxf(mxp[j],__shfl_xor(mxp[j],msk));
      dnp[j]+=__shfl_xor(dnp[j],msk);
    }
  }
  if(ln<16){
    #pragma unroll
    for(int j=0;j<4;j++){ mred[wv*64+j*16+ln]=mxp[j]; dred[wv*64+j*16+ln]=dnp[j]; }
  }
  __syncthreads();
  if(tid<64){
    float mx=fmaxf(fmaxf(mred[tid],mred[64+tid]),fmaxf(mred[128+tid],mred[192+tid]));
    float dn=dred[tid]+dred[64+tid]+dred[128+tid]+dred[192+tid];
    float f=1e-4f*__expf(mx);
    ff_s[tid]=f;
    dinv_s[tid]=1.0f/(dn + f*KS);
  }
  __syncthreads();
  float csr[4];
  #pragma unroll
  for(int r=0;r<4;r++) csr[r]=cs[bh*80 + wv*16+(ln>>4)*4+r];
  u16* og=ob+((size_t)(b_*SEQ+n0))*DIMX + h_*DHEAD;
  #pragma unroll
  for(int j2=0;j2<4;j2++){
    int n=j2*16+(ln&15);
    float f=ff_s[n], di=dinv_s[n];
    u16 pk[4];
    #pragma unroll
    for(int r=0;r<4;r++) pk[r]=f2bf((oc[j2][r]+f*csr[r])*di);
    uint2 pv; pv.x=(unsigned)pk[0]|((unsigned)pk[1]<<16); pv.y=(unsigned)pk[2]|((unsigned)pk[3]<<16);
    *(uint2*)&og[(size_t)n*DIMX + wv*16+(ln>>4)*4]=pv;
  }
}

// ---------------- workspace layout (~204 MiB) ----------------
static constexpr size_t SZ_ACT=(size_t)TOK*DIMX*2;                 // 32 MiB
static constexpr size_t O_X=0;                                     // bf16 trunk
static constexpr size_t O_Y=SZ_ACT, O_Q=2*SZ_ACT, O_K=3*SZ_ACT;
static constexpr size_t O_VT=4*SZ_ACT;                             // 128 MiB
static constexpr size_t SZ_VT=(size_t)NBH*VROWS*SEQ*2;             // 40 MiB
static constexpr size_t O_PART=O_VT+SZ_VT;                         // 168 MiB
static constexpr size_t SZ_PART=(size_t)NBH*NCHUNK*256*80*4;       // 20 MiB
static constexpr size_t O_CTXT=O_PART+SZ_PART;
static constexpr size_t SZ_CTXT=(size_t)NBH*64*NBFX*2;
static constexpr size_t O_KSUM=O_CTXT+SZ_CTXT;
static constexpr size_t SZ_KSUM=(size_t)NBH*NBFX*4;
static constexpr size_t O_MAX=O_KSUM+SZ_KSUM;
static constexpr size_t SZ_MAX=(size_t)NBH*64*4;
static constexpr size_t O_VSUM=O_MAX+SZ_MAX;
static constexpr size_t SZ_VSUM=(size_t)NBH*80*4;
static constexpr size_t O_CS=O_VSUM+SZ_VSUM;
static constexpr size_t SZ_CS=(size_t)NBH*80*4;
static constexpr size_t O_WQKV=(size_t)192*1024*1024;
static_assert(O_CS+SZ_CS <= O_WQKV, "small buffers must end below weight region");
static constexpr size_t SZ_WQKV=(size_t)2*1536*DIMX*2;             // 3 MiB
static constexpr size_t O_WOT=O_WQKV+SZ_WQKV;
static constexpr size_t SZ_W=(size_t)2*DIMX*DIMX*2;                // 1 MiB
static constexpr size_t O_W1T=O_WOT+SZ_W;
static constexpr size_t SZ_W1=(size_t)2*FFD*DIMX*2;                // 4 MiB
static constexpr size_t O_W2T=O_W1T+SZ_W1;
static constexpr size_t O_PJ=O_W2T+SZ_W1;
static constexpr size_t O_QKVB=O_PJ+(size_t)2*NBFX*DHEAD*2;
static constexpr size_t WS_END=O_QKVB+(size_t)2*1536*4;

extern "C" void kernel_launch(void* const* d_in, const int* in_sizes, int n_in,
                              void* d_out, int out_size, void* d_ws, size_t ws_size,
                              hipStream_t stream){
  (void)in_sizes;(void)n_in;(void)out_size;
  const float* xin =(const float*)d_in[0];
  const float* ln1g=(const float*)d_in[1];
  const float* ln1b=(const float*)d_in[2];
  const float* ln2g=(const float*)d_in[3];
  const float* ln2b=(const float*)d_in[4];
  const float* Wq=(const float*)d_in[5];
  const float* bq=(const float*)d_in[6];
  const float* Wk=(const float*)d_in[7];
  const float* bk=(const float*)d_in[8];
  const float* Wv=(const float*)d_in[9];
  const float* bv=(const float*)d_in[10];
  const float* Wo=(const float*)d_in[11];
  const float* bo=(const float*)d_in[12];
  const float* proj=(const float*)d_in[13];
  const float* W1=(const float*)d_in[14];
  const float* b1=(const float*)d_in[15];
  const float* W2=(const float*)d_in[16];
  const float* b2=(const float*)d_in[17];
  float* xout=(float*)d_out;

  if(ws_size < WS_END){
    copy_f32<<<(TOK*DIMX/4)/256,256,0,stream>>>((const float4*)xin,(float4*)xout, TOK*DIMX/4);
    return;
  }

  char* ws=(char*)d_ws;
  u16* xtr  =(u16*)(ws+O_X);      // bf16 residual trunk
  u16* ybuf =(u16*)(ws+O_Y);
  u16* qbuf =(u16*)(ws+O_Q);
  u16* kbuf =(u16*)(ws+O_K);
  u16* vtb  =(u16*)(ws+O_VT);
  float* partb=(float*)(ws+O_PART);
  u16* ctxtb=(u16*)(ws+O_CTXT);
  float* ksumb=(float*)(ws+O_KSUM);
  float* maxb=(float*)(ws+O_MAX);
  float* vsumb=(float*)(ws+O_VSUM);
  float* csb=(float*)(ws+O_CS);
  u16* wqkvt=(u16*)(ws+O_WQKV);
  u16* wot=(u16*)(ws+O_WOT);
  u16* w1t=(u16*)(ws+O_W1T); u16* w2t=(u16*)(ws+O_W2T);
  u16* pjb=(u16*)(ws+O_PJ);
  float* qkvb=(float*)(ws+O_QKVB);
  u16* hbuf=(u16*)(ws+O_Q);   // FF hidden [32768][2048] overlays q/k/vt/part/small regions

  for(int l=0;l<2;l++){
    size_t wo=(size_t)l*DIMX*DIMX;
    convT<<<dim3(16,16),dim3(32,8),0,stream>>>(Wq+wo, wqkvt+(size_t)(l*1536+   0)*DIMX, DIMX, DIMX);
    convT<<<dim3(16,16),dim3(32,8),0,stream>>>(Wk+wo, wqkvt+(size_t)(l*1536+ 512)*DIMX, DIMX, DIMX);
    convT<<<dim3(16,16),dim3(32,8),0,stream>>>(Wv+wo, wqkvt+(size_t)(l*1536+1024)*DIMX, DIMX, DIMX);
    convT<<<dim3(16,16),dim3(32,8),0,stream>>>(Wo+wo, wot+wo, DIMX, DIMX);
    size_t w1o=(size_t)l*DIMX*FFD;
    convT<<<dim3(64,16),dim3(32,8),0,stream>>>(W1+w1o, w1t+w1o, DIMX, FFD);
    convT<<<dim3(16,64),dim3(32,8),0,stream>>>(W2+w1o, w2t+w1o, FFD, DIMX);
  }
  conv_proj<<<(2*NBFX*DHEAD)/256,256,0,stream>>>(proj, pjb, 2*NBFX*DHEAD);
  pack_bias<<<12,256,0,stream>>>(bq,bk,bv,qkvb);

  for(int l=0;l<2;l++){
    const u16* wqkvt_l=wqkvt+(size_t)l*1536*DIMX;
    const u16* wot_l=wot+(size_t)l*DIMX*DIMX;
    const u16* w1t_l=w1t+(size_t)l*DIMX*FFD;
    const u16* w2t_l=w2t+(size_t)l*DIMX*FFD;
    const u16* pj_l =pjb+(size_t)l*NBFX*DHEAD;
    const float* qkvb_l=qkvb+(size_t)l*1536;

    if(l==0) ln_f32<<<TOK/4,256,0,stream>>>(xin, ln1g, ln1b, ybuf);
    else     ln_k<<<TOK/4,256,0,stream>>>(xtr, ln1g+l*DIMX, ln1b+l*DIMX, ybuf);
    fill_vt<<<(NBH*16*SEQ)/256,256,0,stream>>>(vtb);
    gemm256<0,512><<<dim3(6,128),512,0,stream>>>(ybuf, wqkvt_l, qkvb_l, qbuf, vtb, nullptr, 1536);
    vsum_k<<<520,256,0,stream>>>(vtb, vsumb);
    kctx<<<dim3(NCHUNK,32),512,0,stream>>>(kbuf, pj_l, vtb, partb, maxb);
    ctx_reduce<<<dim3(8,32),256,0,stream>>>(partb, maxb, vsumb, ctxtb, ksumb);
    csum_k<<<32,256,0,stream>>>(ctxtb, ksumb, csb);
    q_fused<<<dim3(128,32),256,0,stream>>>(qbuf, pj_l, ctxtb, ksumb, csb, ybuf);
    if(l==0) gemm256<3,512><<<dim3(2,128),512,0,stream>>>(ybuf, wot_l, bo, xtr, nullptr, xin, DIMX);
    else     gemm256<1,512><<<dim3(2,128),512,0,stream>>>(ybuf, wot_l, bo+l*DIMX, xtr, nullptr, nullptr, DIMX);
    ln_k<<<TOK/4,256,0,stream>>>(xtr, ln2g+l*DIMX, ln2b+l*DIMX, ybuf);
    gemm256<2,512><<<dim3(8,128),512,0,stream>>>(ybuf, w1t_l, b1+l*FFD, hbuf, nullptr, nullptr, FFD);
    if(l==0) gemm256<1,2048><<<dim3(2,128),512,0,stream>>>(hbuf, w2t_l, b2, xtr, nullptr, nullptr, DIMX);
    else     gemm256<4,2048><<<dim3(2,128),512,0,stream>>>(hbuf, w2t_l, b2+l*DIMX, xout, nullptr, xtr, DIMX);
  }
}